// Round 14
// baseline (91.093 us; speedup 1.0000x reference)
//
#include <hip/hip_runtime.h>
#include <hip/hip_bf16.h>

// HeteroLinear fused forward on gfx950: out[i] = x[i] @ W[tv[i]] + b[tv[i]]
// N=131072, IN=OUT=256, T=8, tv sorted. HBM floor ~256 MB -> ~42 us.
// R14 = R13's proven wave-level code in 4-wave blocks:
//  - block = 128 rows x 128 cols, W[t] col-half (64 KB) staged via
//    global_load_lds (src-side XOR swizzle) -> 2 blocks/CU co-resident ->
//    block A's stage overlaps block B's compute (two barrier domains/CU)
//  - XCD-bijective swizzle puts both col-halves of a row-group on the SAME
//    XCD consecutively -> half-1's x re-read hits that XCD's L2
//  - dist-2 raw f32x4 x-prefetch (R13's +8% lever, kept)
//  - __float2bfloat16 instead of manual integer f2bf: compiler emits
//    v_cvt_pk_bf16_f32 (m240), ~3x fewer VALU on the A-operand path
//  - acc[2][8]=64 VGPR, total ~110 < 128 cap; plain f32x4 stores

#define NROWS 131072
#define KD 256
#define ND 256
#define BR 128                      // rows per block
#define NRG (NROWS / BR)            // 1024 row-groups
#define NBLK (NRG * 2)              // 2048 (x2 col-halves)

typedef __attribute__((ext_vector_type(8))) short short8;
typedef __attribute__((ext_vector_type(4))) float f32x4;
typedef __attribute__((ext_vector_type(4))) float flt4;

typedef __attribute__((address_space(3))) unsigned int lds_u32_t;
typedef __attribute__((address_space(1))) unsigned int glb_u32_t;

__device__ inline unsigned short f2bf(float f) {
    return __bfloat16_as_ushort(__float2bfloat16(f));   // hw cvt (RNE)
}

// ---- weight prep: wT[t][n][k] = bf16(w[t][k][n]) ----
__global__ __launch_bounds__(256) void prep_weights(const float* __restrict__ w,
                                                    unsigned short* __restrict__ wT) {
    __shared__ unsigned short L[8][264];
    const int t  = blockIdx.x >> 5;
    const int k0 = (blockIdx.x & 31) * 8;
    const int tid = threadIdx.x;

    #pragma unroll
    for (int i = 0; i < 2; ++i) {
        int idx = i * 256 + tid;
        int kr  = idx >> 6;
        int nq  = idx & 63;
        const flt4* src = (const flt4*)(w + ((size_t)t * 256 + k0 + kr) * 256);
        flt4 v = src[nq];
        #pragma unroll
        for (int j = 0; j < 4; ++j) L[kr][nq * 4 + j] = f2bf(v[j]);
    }
    __syncthreads();

    int n = tid;
    short8 v;
    #pragma unroll
    for (int j = 0; j < 8; ++j) v[j] = (short)L[j][n];
    *(short8*)(wT + ((size_t)t * 256 + n) * 256 + k0) = v;
}

// ---- main GEMM: 4-wave blocks, 64 KB W-half in LDS ----
__global__ __launch_bounds__(256) void hetero_gemm(
        const float* __restrict__ x, const int* __restrict__ tv,
        const unsigned short* __restrict__ wT, const float* __restrict__ bias,
        float* __restrict__ out) {
    // W[t] col-half: 128 cols x 256 k bf16, [local col][k], 512 B/col,
    // XOR-swizzled 16B chunks: LDS chunk c of col holds global chunk c^(col&7).
    __shared__ short Bs[128 * KD];           // 64 KiB -> 2 blocks/CU

    const int tid  = threadIdx.x;
    const int lane = tid & 63;
    const int wv   = tid >> 6;               // 4 waves
    const int cl   = lane & 15;
    const int kg   = lane >> 4;
    // XCD-bijective swizzle (nwg=2048 % 8 == 0): both halves of a row-group
    // land on the same XCD, consecutively.
    const int wgid = (blockIdx.x & 7) * (NBLK / 8) + (blockIdx.x >> 3);
    const int rg   = wgid >> 1;
    const int c0   = (wgid & 1) * 128;       // col-half base
    const int r0   = rg * BR;
    const int rw   = r0 + wv * 32;           // wave's 32-row strip

    const int tmin = tv[r0];
    const int tmax = tv[r0 + BR - 1];
    const int ty0  = tv[rw + cl];            // type of row (m=0)
    const int ty1  = tv[rw + 16 + cl];       // type of row (m=1)
    const int s    = cl & 7;                 // swizzle key (col&7 == cl&7)

    // per-lane x row pointers (rows rw+m*16+cl), k-offset kg*8
    const float* xr0 = x + (size_t)(rw + cl) * KD + kg * 8;
    const float* xr1 = x + (size_t)(rw + 16 + cl) * KD + kg * 8;

    for (int t = tmin; t <= tmax; ++t) {
        if (t > tmin) __syncthreads();       // prev-pass reads done before overwrite

        // ---- stage W[t][c0..c0+127][*] -> LDS: 4096 16B chunks, 16 rounds ----
        {
            const unsigned short* Wt = wT + (size_t)t * (KD * ND);
            #pragma unroll
            for (int rnd = 0; rnd < 16; ++rnd) {
                int i   = rnd * 256 + tid;   // chunk index 0..4095
                int lc  = i >> 5;            // local col 0..127
                int c   = i & 31;
                int sc  = c ^ (lc & 7);      // source-side swizzle
                const unsigned short* gp = Wt + (size_t)(c0 + lc) * KD + sc * 8;
                __builtin_amdgcn_global_load_lds(
                    (const glb_u32_t*)gp,
                    (lds_u32_t*)((char*)Bs + (size_t)(rnd * 256 + wv * 64) * 16),
                    16, 0, 0);
            }
        }
        __syncthreads();                     // drain DMA; tile ready

        f32x4 zero = {0.f, 0.f, 0.f, 0.f};
        f32x4 acc[2][8];
        #pragma unroll
        for (int m = 0; m < 2; ++m)
            #pragma unroll
            for (int n = 0; n < 8; ++n) acc[m][n] = zero;

        // dist-2 raw prefetch: two 4x-f32x4 buffers, consume-then-reissue
        f32x4 xbA[4], xbB[4];
        xbA[0] = *(const f32x4*)(xr0);          // ks=0
        xbA[1] = *(const f32x4*)(xr0 + 4);
        xbA[2] = *(const f32x4*)(xr1);
        xbA[3] = *(const f32x4*)(xr1 + 4);
        xbB[0] = *(const f32x4*)(xr0 + 32);     // ks=1
        xbB[1] = *(const f32x4*)(xr0 + 36);
        xbB[2] = *(const f32x4*)(xr1 + 32);
        xbB[3] = *(const f32x4*)(xr1 + 36);

        auto step = [&](f32x4 (&xb)[4], int ks) {
            short8 a[2];
            #pragma unroll
            for (int m = 0; m < 2; ++m) {
                #pragma unroll
                for (int j = 0; j < 4; ++j) {
                    a[m][j]     = (short)f2bf(xb[2 * m][j]);
                    a[m][4 + j] = (short)f2bf(xb[2 * m + 1][j]);
                }
            }
            if (ks + 2 < 8) {                // reissue freed buffer for ks+2
                xb[0] = *(const f32x4*)(xr0 + (ks + 2) * 32);
                xb[1] = *(const f32x4*)(xr0 + (ks + 2) * 32 + 4);
                xb[2] = *(const f32x4*)(xr1 + (ks + 2) * 32);
                xb[3] = *(const f32x4*)(xr1 + (ks + 2) * 32 + 4);
            }
            #pragma unroll
            for (int n = 0; n < 8; ++n) {
                int lc = n * 16 + cl;                 // local col
                int kc = ((ks << 2) | kg) ^ s;        // swizzled 16B chunk
                short8 b = *(const short8*)((char*)Bs + (size_t)lc * 512 + (kc << 4));
                // swapped operands: D[w-col][x-row]
                acc[0][n] = __builtin_amdgcn_mfma_f32_16x16x32_bf16(b, a[0], acc[0][n], 0, 0, 0);
                acc[1][n] = __builtin_amdgcn_mfma_f32_16x16x32_bf16(b, a[1], acc[1][n], 0, 0, 0);
            }
        };
        step(xbA, 0); step(xbB, 1); step(xbA, 2); step(xbB, 3);
        step(xbA, 4); step(xbB, 5); step(xbA, 6); step(xbB, 7);

        // ---- epilogue: rows rw+m*16+cl, cols c0+n*16+kg*4 (plain stores) ----
        #pragma unroll
        for (int m = 0; m < 2; ++m) {
            int tym = (m == 0) ? ty0 : ty1;
            if (tym == t) {
                float* orow = out + (size_t)(rw + m * 16 + cl) * ND + c0 + kg * 4;
                #pragma unroll
                for (int n = 0; n < 8; ++n) {
                    f32x4 bv = *(const f32x4*)(bias + (size_t)t * ND + c0 + n * 16 + kg * 4);
                    *(f32x4*)(orow + n * 16) = acc[m][n] + bv;
                }
            }
        }
    }
}

extern "C" void kernel_launch(void* const* d_in, const int* in_sizes, int n_in,
                              void* d_out, int out_size, void* d_ws, size_t ws_size,
                              hipStream_t stream) {
    const float* x    = (const float*)d_in[0];
    const int*   tv   = (const int*)d_in[1];
    const float* w    = (const float*)d_in[2];
    const float* bias = (const float*)d_in[3];
    float* out = (float*)d_out;
    unsigned short* wT = (unsigned short*)d_ws;   // 8*256*256*2 = 1 MiB

    prep_weights<<<dim3(256), dim3(256), 0, stream>>>(w, wT);
    hetero_gemm<<<dim3(NBLK), dim3(256), 0, stream>>>(x, tv, wT, bias, out);
}

// Round 15
// 69.859 us; speedup vs baseline: 1.3040x; 1.3040x over previous
//
#include <hip/hip_runtime.h>
#include <hip/hip_bf16.h>

// HeteroLinear fused forward on gfx950: out[i] = x[i] @ W[tv[i]] + b[tv[i]]
// N=131072, IN=OUT=256, T=8, tv sorted. HBM floor ~200-256 MB -> ~41 us.
// R15: fix the x-stream's outstanding-bytes limit (R13: 128 B/wave in regs
// vs ~22 KB/CU Little's-law need). x now flows through a WAVE-PRIVATE
// 2-slot LDS ring filled by global_load_lds (1 KB/instr, vmcnt-tracked,
// zero VGPR): in-flight x = 8 KB/wave x 8 waves = 64 KB/CU. Counted
// s_waitcnt vmcnt(4) per ks (never drain to 0, T4); asm ds_read_b128 +
// lgkmcnt(0) + sched_barrier (rule 18); DMA(ks+2) issued into the
// just-read slot after lgkm drain. Wave-private => NO barriers for x.
// Block = 256 rows x 128 cols (XCD-paired col-halves), 8 waves; W-half
// 64 KB LDS staged once/pass (R13's proven DMA + XOR swizzle). LDS 128 KB.

#define NROWS 131072
#define KD 256
#define ND 256
#define BM 256                      // rows per block
#define NBLK ((NROWS / BM) * 2)     // 1024 (x2 col-halves)

typedef __attribute__((ext_vector_type(8))) short short8;
typedef __attribute__((ext_vector_type(4))) float f32x4;
typedef __attribute__((ext_vector_type(4))) float flt4;

typedef __attribute__((address_space(3))) unsigned int lds_u32_t;
typedef __attribute__((address_space(1))) unsigned int glb_u32_t;

__device__ inline unsigned short f2bf(float f) {
    unsigned int u = __float_as_uint(f);
    u += 0x7FFFu + ((u >> 16) & 1u);   // RNE
    return (unsigned short)(u >> 16);
}

__device__ inline f32x4 lds_read_b128(unsigned addr) {
    f32x4 v;
    asm volatile("ds_read_b128 %0, %1" : "=v"(v) : "v"(addr));
    return v;
}

// ---- weight prep: wT[t][n][k] = bf16(w[t][k][n]) ----
__global__ __launch_bounds__(256) void prep_weights(const float* __restrict__ w,
                                                    unsigned short* __restrict__ wT) {
    __shared__ unsigned short L[8][264];
    const int t  = blockIdx.x >> 5;
    const int k0 = (blockIdx.x & 31) * 8;
    const int tid = threadIdx.x;

    #pragma unroll
    for (int i = 0; i < 2; ++i) {
        int idx = i * 256 + tid;
        int kr  = idx >> 6;
        int nq  = idx & 63;
        const flt4* src = (const flt4*)(w + ((size_t)t * 256 + k0 + kr) * 256);
        flt4 v = src[nq];
        #pragma unroll
        for (int j = 0; j < 4; ++j) L[kr][nq * 4 + j] = f2bf(v[j]);
    }
    __syncthreads();

    int n = tid;
    short8 v;
    #pragma unroll
    for (int j = 0; j < 8; ++j) v[j] = (short)L[j][n];
    *(short8*)(wT + ((size_t)t * 256 + n) * 256 + k0) = v;
}

// ---- main GEMM ----
__global__ __launch_bounds__(512) void hetero_gemm(
        const float* __restrict__ x, const int* __restrict__ tv,
        const unsigned short* __restrict__ wT, const float* __restrict__ bias,
        float* __restrict__ out) {
    // W col-half: 128 cols x 256 k bf16, [col][k], XOR-swizzled 16B chunks.
    __shared__ short Bs[128 * KD];           // 64 KiB
    // x ring: [buf 2][wave 8][row 32][k-chunk 8 x 16B], swizzled chunks.
    __shared__ float Xs[2 * 8 * 32 * 32];    // 64 KiB

    const int tid  = threadIdx.x;
    const int lane = tid & 63;
    const int wv   = tid >> 6;               // 8 waves
    const int cl   = lane & 15;
    const int kg   = lane >> 4;
    // XCD-bijective swizzle (1024 % 8 == 0): both col-halves of a row-group
    // land consecutively on the same XCD -> x re-read L2-hits.
    const int wgid = (blockIdx.x & 7) * (NBLK / 8) + (blockIdx.x >> 3);
    const int rg   = wgid >> 1;
    const int c0   = (wgid & 1) * 128;       // col-half base
    const int r0   = rg * BM;
    const int rw   = r0 + wv * 32;           // wave's 32-row strip

    const int tmin = tv[r0];
    const int tmax = tv[r0 + BM - 1];
    const int ty0  = tv[rw + cl];
    const int ty1  = tv[rw + 16 + cl];
    const int s    = cl & 7;                 // swizzle key

    const unsigned xwbase = (unsigned)(uintptr_t)&Xs[wv * 1024];  // buf0 base

    // ---- per-wave x slice DMA: slice ks (32 rows x 32 floats) -> buf ks&1 ----
    auto DMA_X = [&](int ks) {
        const int buf = ks & 1;
        #pragma unroll
        for (int i = 0; i < 4; ++i) {
            // lane l: row 8i + (l>>3), 16B chunk (l&7) XOR row&7 (src-side swz)
            const float* gp = x + (size_t)(rw + 8 * i + (lane >> 3)) * KD
                                + ks * 32 + (((lane & 7) ^ (lane >> 3)) << 2);
            __builtin_amdgcn_global_load_lds(
                (const glb_u32_t*)gp,
                (lds_u32_t*)&Xs[(buf * 8 + wv) * 1024 + i * 256],
                16, 0, 0);
        }
    };

    for (int t = tmin; t <= tmax; ++t) {
        if (t > tmin) __syncthreads();       // prev-pass reads done

        // ---- stage W[t] col-half -> LDS (4096 chunks, 8 rounds) ----
        {
            const unsigned short* Wt = wT + (size_t)t * (KD * ND);
            #pragma unroll
            for (int rnd = 0; rnd < 8; ++rnd) {
                int i  = rnd * 512 + tid;    // chunk 0..4095
                int lc = i >> 5;             // local col 0..127
                int c  = i & 31;
                int sc = c ^ (lc & 7);
                const unsigned short* gp = Wt + (size_t)(c0 + lc) * KD + sc * 8;
                __builtin_amdgcn_global_load_lds(
                    (const glb_u32_t*)gp,
                    (lds_u32_t*)((char*)Bs + (size_t)(rnd * 512 + wv * 64) * 16),
                    16, 0, 0);
            }
        }
        DMA_X(0); DMA_X(1);                  // ring prologue rides with stage
        __syncthreads();                     // drains W stage (+ prologue)

        f32x4 zero = {0.f, 0.f, 0.f, 0.f};
        f32x4 acc[2][8];
        #pragma unroll
        for (int m = 0; m < 2; ++m)
            #pragma unroll
            for (int n = 0; n < 8; ++n) acc[m][n] = zero;

        #define KSTEP(ks)                                                          \
        {                                                                          \
            if ((ks) < 7) asm volatile("s_waitcnt vmcnt(4)" ::: "memory");         \
            else          asm volatile("s_waitcnt vmcnt(0)" ::: "memory");         \
            __builtin_amdgcn_sched_barrier(0);                                     \
            const unsigned sb = xwbase + (((ks) & 1) << 15);                       \
            f32x4 v00 = lds_read_b128(sb + cl * 128 + (((2 * kg + 0) ^ s) << 4));  \
            f32x4 v01 = lds_read_b128(sb + cl * 128 + (((2 * kg + 1) ^ s) << 4));  \
            f32x4 v10 = lds_read_b128(sb + (16 + cl) * 128 + (((2 * kg + 0) ^ s) << 4)); \
            f32x4 v11 = lds_read_b128(sb + (16 + cl) * 128 + (((2 * kg + 1) ^ s) << 4)); \
            asm volatile("s_waitcnt lgkmcnt(0)" ::: "memory");                     \
            __builtin_amdgcn_sched_barrier(0);                                     \
            if ((ks) < 6) DMA_X((ks) + 2);   /* overwrite just-read slot */        \
            short8 a0, a1;                                                         \
            _Pragma("unroll")                                                      \
            for (int j = 0; j < 4; ++j) {                                          \
                a0[j]     = (short)f2bf(v00[j]);                                   \
                a0[4 + j] = (short)f2bf(v01[j]);                                   \
                a1[j]     = (short)f2bf(v10[j]);                                   \
                a1[4 + j] = (short)f2bf(v11[j]);                                   \
            }                                                                      \
            _Pragma("unroll")                                                      \
            for (int n = 0; n < 8; ++n) {                                          \
                int lc = n * 16 + cl;                                              \
                int kc = (((ks) << 2) | kg) ^ s;                                   \
                short8 b = *(const short8*)((char*)Bs + (size_t)lc * 512 + (kc << 4)); \
                acc[0][n] = __builtin_amdgcn_mfma_f32_16x16x32_bf16(b, a0, acc[0][n], 0, 0, 0); \
                acc[1][n] = __builtin_amdgcn_mfma_f32_16x16x32_bf16(b, a1, acc[1][n], 0, 0, 0); \
            }                                                                      \
        }
        KSTEP(0) KSTEP(1) KSTEP(2) KSTEP(3)
        KSTEP(4) KSTEP(5) KSTEP(6) KSTEP(7)
        #undef KSTEP

        // ---- epilogue: rows rw+m*16+cl, cols c0+n*16+kg*4 (plain stores) ----
        #pragma unroll
        for (int m = 0; m < 2; ++m) {
            int tym = (m == 0) ? ty0 : ty1;
            if (tym == t) {
                float* orow = out + (size_t)(rw + m * 16 + cl) * ND + c0 + kg * 4;
                #pragma unroll
                for (int n = 0; n < 8; ++n) {
                    f32x4 bv = *(const f32x4*)(bias + (size_t)t * ND + c0 + n * 16 + kg * 4);
                    *(f32x4*)(orow + n * 16) = acc[m][n] + bv;
                }
            }
        }
    }
}

extern "C" void kernel_launch(void* const* d_in, const int* in_sizes, int n_in,
                              void* d_out, int out_size, void* d_ws, size_t ws_size,
                              hipStream_t stream) {
    const float* x    = (const float*)d_in[0];
    const int*   tv   = (const int*)d_in[1];
    const float* w    = (const float*)d_in[2];
    const float* bias = (const float*)d_in[3];
    float* out = (float*)d_out;
    unsigned short* wT = (unsigned short*)d_ws;   // 8*256*256*2 = 1 MiB

    prep_weights<<<dim3(256), dim3(256), 0, stream>>>(w, wT);
    hetero_gemm<<<dim3(NBLK), dim3(512), 0, stream>>>(x, tv, wT, bias, out);
}